// Round 2
// baseline (977.417 us; speedup 1.0000x reference)
//
#include <hip/hip_runtime.h>
#include <stdint.h>

// OutliersQLinearUnstruct: out[b][o] = sum_i x[b][i]*w_eff[o][i] + bias[o]
//   w_eff = mask ? w : scale_o * sign(w - mean_o)
//   mean_o  = mean(wz_row)   (wz = mask ? 0 : w, mean over ALL IC incl. zeros)
//   scale_o = mean(|wz_row|)
// OC=11008, IC=4096, B=32. x/w/bias f32; mask staged as int32 (nonzero = outlier).
//
// Structure:
//   K1 stats+pack: 1 block/row; reads w row + int32 mask row; writes
//                  {mean,scale} and a 1-bit/elem packed mask (64 u64/row).
//   K2 gemv      : 172 o-tiles x SK=2 k-splits; thread = (row o, 8 batches);
//                  reads w + packed bits; partials -> ws (deterministic, no atomics).
//   K3 reduce    : out = part0 + part1 + bias.

#define OC 11008
#define IC 4096
#define BATCH 32
#define O_T 64
#define SK 2
#define KCH (IC / SK)  // 2048

__global__ __launch_bounds__(256) void stats_kernel(
    const int* __restrict__ mask, const float* __restrict__ w,
    float2* __restrict__ stats, unsigned long long* __restrict__ packed,
    int do_pack) {
  const int o = blockIdx.x;
  const int t = threadIdx.x;
  const float* wr = w + (size_t)o * IC;
  const int* mr = mask + (size_t)o * IC;

  // 16 elements/thread: 4x float4 + 4x int4
  const float4* w4 = reinterpret_cast<const float4*>(wr) + t * 4;
  const int4* m4 = reinterpret_cast<const int4*>(mr) + t * 4;

  float s1 = 0.f, s2 = 0.f;
  uint32_t bits = 0;
#pragma unroll
  for (int q = 0; q < 4; ++q) {
    const float4 wv = w4[q];
    const int4 mv = m4[q];
    const float vals[4] = {wv.x, wv.y, wv.z, wv.w};
    const int ms[4] = {mv.x, mv.y, mv.z, mv.w};
#pragma unroll
    for (int e = 0; e < 4; ++e) {
      const bool msk = (ms[e] != 0);
      if (msk) bits |= (1u << (q * 4 + e));
      const float wz = msk ? 0.f : vals[e];
      s1 += wz;
      s2 += fabsf(wz);
    }
  }

  // wave-64 butterfly-free reduce (shfl_down), then cross-wave via LDS
#pragma unroll
  for (int off = 32; off > 0; off >>= 1) {
    s1 += __shfl_down(s1, off);
    s2 += __shfl_down(s2, off);
  }
  __shared__ float r1[4], r2[4];
  __shared__ unsigned short pb[256];
  pb[t] = (unsigned short)bits;
  const int lane = t & 63, wv_id = t >> 6;
  if (lane == 0) { r1[wv_id] = s1; r2[wv_id] = s2; }
  __syncthreads();
  if (t == 0) {
    const float a = r1[0] + r1[1] + r1[2] + r1[3];
    const float b = r2[0] + r2[1] + r2[2] + r2[3];
    stats[o] = make_float2(a * (1.0f / IC), b * (1.0f / IC));
  }
  if (do_pack && t < 64) {
    // word t covers elements t*64 .. t*64+63 (threads 4t..4t+3's 16-bit chunks)
    unsigned long long wbits =
        (unsigned long long)pb[4 * t + 0] |
        ((unsigned long long)pb[4 * t + 1] << 16) |
        ((unsigned long long)pb[4 * t + 2] << 32) |
        ((unsigned long long)pb[4 * t + 3] << 48);
    packed[(size_t)o * (IC / 64) + t] = wbits;
  }
}

template <int PACKED>
__global__ __launch_bounds__(256) void gemv_kernel(
    const float* __restrict__ x, const float* __restrict__ w,
    const int* __restrict__ mask, const unsigned long long* __restrict__ packed,
    const float2* __restrict__ stats, float* __restrict__ part) {
  const int bx = blockIdx.x;
  const int tile = bx >> 1;
  const int sk = bx & 1;
  const int t = threadIdx.x;
  const int o = tile * O_T + (t >> 2);  // 64 rows/block; 4 lanes share a row
  const int bg = t & 3;                 // batch group: b = bg*8 + j

  const float2 st = stats[o];
  const float m = st.x, s = st.y;
  const float* wr = w + (size_t)o * IC;
  const int* mi = mask + (size_t)o * IC;
  const unsigned long long* pr =
      packed + (size_t)o * (IC / 64) + (size_t)sk * (KCH / 64);
  const float* xb = x + (size_t)(bg * 8) * IC;

  float acc[8];
#pragma unroll
  for (int j = 0; j < 8; ++j) acc[j] = 0.f;

  const int i0 = sk * KCH;
  for (int wI = 0; wI < KCH / 64; ++wI) {
    unsigned long long word = 0;
    if (PACKED) word = pr[wI];
#pragma unroll 4
    for (int ss = 0; ss < 16; ++ss) {
      const int i = i0 + wI * 64 + ss * 4;
      const float4 wv = *reinterpret_cast<const float4*>(wr + i);
      uint32_t mb;
      if (PACKED) {
        mb = (uint32_t)(word >> (ss * 4)) & 0xFu;
      } else {
        const int4 mv = *reinterpret_cast<const int4*>(mi + i);
        mb = (uint32_t)(mv.x != 0) | ((uint32_t)(mv.y != 0) << 1) |
             ((uint32_t)(mv.z != 0) << 2) | ((uint32_t)(mv.w != 0) << 3);
      }
      const float we0 = (mb & 1u) ? wv.x : copysignf(s, wv.x - m);
      const float we1 = (mb & 2u) ? wv.y : copysignf(s, wv.y - m);
      const float we2 = (mb & 4u) ? wv.z : copysignf(s, wv.z - m);
      const float we3 = (mb & 8u) ? wv.w : copysignf(s, wv.w - m);
#pragma unroll
      for (int j = 0; j < 8; ++j) {
        const float4 xv =
            *reinterpret_cast<const float4*>(xb + (size_t)j * IC + i);
        acc[j] += xv.x * we0;
        acc[j] += xv.y * we1;
        acc[j] += xv.z * we2;
        acc[j] += xv.w * we3;
      }
    }
  }

#pragma unroll
  for (int j = 0; j < 8; ++j) {
    const int b = bg * 8 + j;
    part[(size_t)sk * (BATCH * OC) + (size_t)b * OC + o] = acc[j];
  }
}

__global__ __launch_bounds__(256) void reduce_kernel(
    const float* __restrict__ part, const float* __restrict__ bias,
    float* __restrict__ out) {
  const int idx = blockIdx.x * 256 + threadIdx.x;
  if (idx < BATCH * OC) {
    const int o = idx % OC;
    out[idx] = part[idx] + part[BATCH * OC + idx] + bias[o];
  }
}

extern "C" void kernel_launch(void* const* d_in, const int* in_sizes, int n_in,
                              void* d_out, int out_size, void* d_ws,
                              size_t ws_size, hipStream_t stream) {
  const float* x = (const float*)d_in[0];     // [32][1][4096] f32
  const float* w = (const float*)d_in[1];     // [11008][4096] f32
  const float* bias = (const float*)d_in[2];  // [11008] f32
  const int* mask = (const int*)d_in[3];      // [11008][4096] int32 (0/1)
  float* out = (float*)d_out;                 // [32][1][11008] f32

  const size_t need_stats = (size_t)OC * sizeof(float2);          // 88 KB
  const size_t need_part = (size_t)SK * BATCH * OC * sizeof(float);  // 2.8 MB
  const size_t need_packed = (size_t)OC * (IC / 64) * 8;          // 5.6 MB

  float2* stats = (float2*)d_ws;
  float* part = (float*)((char*)d_ws + need_stats);
  unsigned long long* packed =
      (unsigned long long*)((char*)d_ws + need_stats + need_part);
  const bool do_pack = ws_size >= need_stats + need_part + need_packed;

  stats_kernel<<<OC, 256, 0, stream>>>(mask, w, stats,
                                       do_pack ? packed : nullptr,
                                       do_pack ? 1 : 0);
  if (do_pack)
    gemv_kernel<1><<<(OC / O_T) * SK, 256, 0, stream>>>(x, w, mask, packed,
                                                        stats, part);
  else
    gemv_kernel<0><<<(OC / O_T) * SK, 256, 0, stream>>>(x, w, mask, packed,
                                                        stats, part);
  reduce_kernel<<<(BATCH * OC + 255) / 256, 256, 0, stream>>>(part, bias, out);
}

// Round 3
// 165.475 us; speedup vs baseline: 5.9067x; 5.9067x over previous
//
#include <hip/hip_runtime.h>
#include <stdint.h>

// OutliersQLinearUnstruct: out[b][o] = sum_i x[b][i]*w_eff[o][i] + bias[o]
//   w_eff = mask ? w : scale_o * sign(w - mean_o)
//   mean_o  = mean(wz_row), scale_o = mean(|wz_row|), wz = mask ? 0 : w
// OC=11008, IC=4096, B=32. x/w/bias f32; mask staged as int32 (nonzero = outlier).
//
// R3 structure:
//   K1 stats+pack (unchanged): per-row {mean,scale} + 1-bit packed mask.
//   K2 gemv: wave = 16 i-lanes x 4 b-groups, 8 rows/wave (x-reuse R=8),
//            acc[8][8] in-lane, 4-stage shfl_xor reduce over i-lanes.
//            Grid = (OC/32) x SK=4 -> 1376 blocks. Partials in ws.
//   K3 reduce: out = sum_sk part + bias.

#define OC 11008
#define IC 4096
#define BATCH 32
#define SK 4
#define KCH (IC / SK)  // 1024

__global__ __launch_bounds__(256) void stats_kernel(
    const int* __restrict__ mask, const float* __restrict__ w,
    float2* __restrict__ stats, unsigned long long* __restrict__ packed,
    int do_pack) {
  const int o = blockIdx.x;
  const int t = threadIdx.x;
  const float* wr = w + (size_t)o * IC;
  const int* mr = mask + (size_t)o * IC;

  const float4* w4 = reinterpret_cast<const float4*>(wr) + t * 4;
  const int4* m4 = reinterpret_cast<const int4*>(mr) + t * 4;

  float s1 = 0.f, s2 = 0.f;
  uint32_t bits = 0;
#pragma unroll
  for (int q = 0; q < 4; ++q) {
    const float4 wv = w4[q];
    const int4 mv = m4[q];
    const float vals[4] = {wv.x, wv.y, wv.z, wv.w};
    const int ms[4] = {mv.x, mv.y, mv.z, mv.w};
#pragma unroll
    for (int e = 0; e < 4; ++e) {
      const bool msk = (ms[e] != 0);
      if (msk) bits |= (1u << (q * 4 + e));
      const float wz = msk ? 0.f : vals[e];
      s1 += wz;
      s2 += fabsf(wz);
    }
  }

#pragma unroll
  for (int off = 32; off > 0; off >>= 1) {
    s1 += __shfl_down(s1, off);
    s2 += __shfl_down(s2, off);
  }
  __shared__ float r1[4], r2[4];
  __shared__ unsigned short pb[256];
  pb[t] = (unsigned short)bits;
  const int lane = t & 63, wv_id = t >> 6;
  if (lane == 0) { r1[wv_id] = s1; r2[wv_id] = s2; }
  __syncthreads();
  if (t == 0) {
    const float a = r1[0] + r1[1] + r1[2] + r1[3];
    const float b = r2[0] + r2[1] + r2[2] + r2[3];
    stats[o] = make_float2(a * (1.0f / IC), b * (1.0f / IC));
  }
  if (do_pack && t < 64) {
    unsigned long long wbits =
        (unsigned long long)pb[4 * t + 0] |
        ((unsigned long long)pb[4 * t + 1] << 16) |
        ((unsigned long long)pb[4 * t + 2] << 32) |
        ((unsigned long long)pb[4 * t + 3] << 48);
    packed[(size_t)o * (IC / 64) + t] = wbits;
  }
}

template <int PACKED>
__global__ __launch_bounds__(256) void gemv_kernel(
    const float* __restrict__ x, const float* __restrict__ w,
    const int* __restrict__ mask, const unsigned long long* __restrict__ packed,
    const float2* __restrict__ stats, float* __restrict__ part) {
  const int bx = blockIdx.x;
  const int tile = bx >> 2;   // 344 o-tiles of 32 rows
  const int sk = bx & 3;      // k-split
  const int t = threadIdx.x;
  const int wvid = t >> 6;
  const int lane = t & 63;
  const int il = lane & 15;   // i-lane (coalescing dimension)
  const int bg = lane >> 4;   // b-group: b = bg*8 + j

  const int row0 = tile * 32 + wvid * 8;
  const int i0 = sk * KCH;

  const float* wr0 = w + (size_t)row0 * IC;
  const int* mk0 = mask + (size_t)row0 * IC;
  const unsigned long long* pk0 = packed + (size_t)row0 * (IC / 64);
  const float* xb = x + (size_t)(bg * 8) * IC;

  float2 stv[8];
#pragma unroll
  for (int r = 0; r < 8; ++r) stv[r] = stats[row0 + r];

  float acc[8][8];
#pragma unroll
  for (int r = 0; r < 8; ++r)
#pragma unroll
    for (int j = 0; j < 8; ++j) acc[r][j] = 0.f;

  for (int s_ = 0; s_ < KCH / 64; ++s_) {  // 16 steps, 64 i each
    const int ib = i0 + (s_ << 6);
    const int i = ib + (il << 2);

    float4 wf[8];
    uint32_t nib[8];
#pragma unroll
    for (int r = 0; r < 8; ++r)
      wf[r] = *reinterpret_cast<const float4*>(wr0 + (size_t)r * IC + i);
    if (PACKED) {
#pragma unroll
      for (int r = 0; r < 8; ++r) {
        const unsigned long long word = pk0[(size_t)r * (IC / 64) + (ib >> 6)];
        nib[r] = (uint32_t)(word >> (il << 2)) & 0xFu;
      }
    } else {
#pragma unroll
      for (int r = 0; r < 8; ++r) {
        const int4 mv =
            *reinterpret_cast<const int4*>(mk0 + (size_t)r * IC + i);
        nib[r] = (uint32_t)(mv.x != 0) | ((uint32_t)(mv.y != 0) << 1) |
                 ((uint32_t)(mv.z != 0) << 2) | ((uint32_t)(mv.w != 0) << 3);
      }
    }

#pragma unroll
    for (int r = 0; r < 8; ++r) {
      const float m = stv[r].x, sc = stv[r].y;
      float4 v = wf[r];
      v.x = (nib[r] & 1u) ? v.x : copysignf(sc, v.x - m);
      v.y = (nib[r] & 2u) ? v.y : copysignf(sc, v.y - m);
      v.z = (nib[r] & 4u) ? v.z : copysignf(sc, v.z - m);
      v.w = (nib[r] & 8u) ? v.w : copysignf(sc, v.w - m);
      wf[r] = v;
    }

#pragma unroll
    for (int j = 0; j < 8; ++j) {
      const float4 xv =
          *reinterpret_cast<const float4*>(xb + (size_t)j * IC + i);
#pragma unroll
      for (int r = 0; r < 8; ++r) {
        acc[r][j] += wf[r].x * xv.x;
        acc[r][j] += wf[r].y * xv.y;
        acc[r][j] += wf[r].z * xv.z;
        acc[r][j] += wf[r].w * xv.w;
      }
    }
  }

  // reduce over the 16 i-lanes (xor offsets stay within the 16-lane group)
#pragma unroll
  for (int off = 8; off >= 1; off >>= 1) {
#pragma unroll
    for (int r = 0; r < 8; ++r)
#pragma unroll
      for (int j = 0; j < 8; ++j)
        acc[r][j] += __shfl_xor(acc[r][j], off);
  }

  if (il == 0) {
#pragma unroll
    for (int r = 0; r < 8; ++r)
#pragma unroll
      for (int j = 0; j < 8; ++j)
        part[(size_t)sk * (BATCH * OC) + (size_t)(bg * 8 + j) * OC +
             (row0 + r)] = acc[r][j];
  }
}

__global__ __launch_bounds__(256) void reduce_kernel(
    const float* __restrict__ part, const float* __restrict__ bias,
    float* __restrict__ out) {
  const int idx = blockIdx.x * 256 + threadIdx.x;
  if (idx < BATCH * OC) {
    const int o = idx % OC;
    float v = bias[o];
#pragma unroll
    for (int sk = 0; sk < SK; ++sk) v += part[(size_t)sk * (BATCH * OC) + idx];
    out[idx] = v;
  }
}

extern "C" void kernel_launch(void* const* d_in, const int* in_sizes, int n_in,
                              void* d_out, int out_size, void* d_ws,
                              size_t ws_size, hipStream_t stream) {
  const float* x = (const float*)d_in[0];     // [32][1][4096] f32
  const float* w = (const float*)d_in[1];     // [11008][4096] f32
  const float* bias = (const float*)d_in[2];  // [11008] f32
  const int* mask = (const int*)d_in[3];      // [11008][4096] int32 (0/1)
  float* out = (float*)d_out;                 // [32][1][11008] f32

  const size_t need_stats = (size_t)OC * sizeof(float2);             // 88 KB
  const size_t need_part = (size_t)SK * BATCH * OC * sizeof(float);  // 5.6 MB
  const size_t need_packed = (size_t)OC * (IC / 64) * 8;             // 5.6 MB

  float2* stats = (float2*)d_ws;
  float* part = (float*)((char*)d_ws + need_stats);
  unsigned long long* packed =
      (unsigned long long*)((char*)d_ws + need_stats + need_part);
  const bool do_pack = ws_size >= need_stats + need_part + need_packed;

  stats_kernel<<<OC, 256, 0, stream>>>(mask, w, stats,
                                       do_pack ? packed : nullptr,
                                       do_pack ? 1 : 0);
  if (do_pack)
    gemv_kernel<1><<<(OC / 32) * SK, 256, 0, stream>>>(x, w, mask, packed,
                                                       stats, part);
  else
    gemv_kernel<0><<<(OC / 32) * SK, 256, 0, stream>>>(x, w, mask, packed,
                                                       stats, part);
  reduce_kernel<<<(BATCH * OC + 255) / 256, 256, 0, stream>>>(part, bias, out);
}

// Round 4
// 121.167 us; speedup vs baseline: 8.0667x; 1.3657x over previous
//
#include <hip/hip_runtime.h>
#include <stdint.h>

// OutliersQLinearUnstruct: out[b][o] = sum_i x[b][i]*w_eff[o][i] + bias[o]
//   w_eff = mask ? w : scale_o * sign(w - mean_o)
//   mean_o = mean(wz_row), scale_o = mean(|wz_row|), wz = mask ? 0 : w
// OC=11008, IC=4096, B=32. x/w/bias f32; mask int32 (nonzero = outlier).
//
// R4: K1 fused stats+transform -> w_eff bf16 (+ x->bf16 cast),
//     K2 MFMA bf16 GEMM (split-K=8, no LDS: both frags are 16B K-major loads),
//     K3 reduce + bias. Fallback to R3-style f32 path if ws too small.

#define OC 11008
#define IC 4096
#define BATCH 32
#define SKM 8              // split-K for MFMA gemm
#define SKF 4              // split-K for fallback gemv

typedef __attribute__((ext_vector_type(8))) short short8;
typedef __attribute__((ext_vector_type(4))) float floatx4;

static __device__ __forceinline__ unsigned short f2bf(float f) {
  uint32_t u = __builtin_bit_cast(uint32_t, f);
  uint32_t r = (u + 0x7fffu + ((u >> 16) & 1u)) >> 16;
  return (unsigned short)r;
}

// ---------------- K1: fused stats + transform + bf16 stores ----------------
// blocks 0..OC-1: row path. blocks OC..OC+31: x-cast path (one b-row each).
__global__ __launch_bounds__(256) void fuse_kernel(
    const float* __restrict__ w, const int* __restrict__ mask,
    const float* __restrict__ x, unsigned short* __restrict__ weff,
    unsigned short* __restrict__ xbf) {
  const int blk = blockIdx.x;
  const int t = threadIdx.x;

  if (blk >= OC) {  // x cast: row b = blk - OC
    const float* xr = x + (size_t)(blk - OC) * IC;
    unsigned short* xo = xbf + (size_t)(blk - OC) * IC;
#pragma unroll
    for (int q = 0; q < 4; ++q) {
      const int i = (q << 10) + (t << 2);
      const float4 v = *reinterpret_cast<const float4*>(xr + i);
      ushort4 u;
      u.x = f2bf(v.x); u.y = f2bf(v.y); u.z = f2bf(v.z); u.w = f2bf(v.w);
      *reinterpret_cast<ushort4*>(xo + i) = u;
    }
    return;
  }

  const float* wr = w + (size_t)blk * IC;
  const int* mr = mask + (size_t)blk * IC;

  float4 wv[4];
  uint32_t nib[4];
  float s1 = 0.f, s2 = 0.f;
#pragma unroll
  for (int q = 0; q < 4; ++q) {
    const int i = (q << 10) + (t << 2);  // lane-contiguous: 1KB/wave-instr
    wv[q] = *reinterpret_cast<const float4*>(wr + i);
    const int4 mv = *reinterpret_cast<const int4*>(mr + i);
    uint32_t nb = (uint32_t)(mv.x != 0) | ((uint32_t)(mv.y != 0) << 1) |
                  ((uint32_t)(mv.z != 0) << 2) | ((uint32_t)(mv.w != 0) << 3);
    nib[q] = nb;
    const float z0 = (nb & 1u) ? 0.f : wv[q].x;
    const float z1 = (nb & 2u) ? 0.f : wv[q].y;
    const float z2 = (nb & 4u) ? 0.f : wv[q].z;
    const float z3 = (nb & 8u) ? 0.f : wv[q].w;
    s1 += z0 + z1 + z2 + z3;
    s2 += fabsf(z0) + fabsf(z1) + fabsf(z2) + fabsf(z3);
  }

#pragma unroll
  for (int off = 32; off > 0; off >>= 1) {
    s1 += __shfl_down(s1, off);
    s2 += __shfl_down(s2, off);
  }
  __shared__ float r1[4], r2[4];
  if ((t & 63) == 0) { r1[t >> 6] = s1; r2[t >> 6] = s2; }
  __syncthreads();
  const float mean = (r1[0] + r1[1] + r1[2] + r1[3]) * (1.0f / IC);
  const float scale = (r2[0] + r2[1] + r2[2] + r2[3]) * (1.0f / IC);

  unsigned short* wo = weff + (size_t)blk * IC;
#pragma unroll
  for (int q = 0; q < 4; ++q) {
    const int i = (q << 10) + (t << 2);
    float4 v = wv[q];
    const uint32_t nb = nib[q];
    v.x = (nb & 1u) ? v.x : copysignf(scale, v.x - mean);
    v.y = (nb & 2u) ? v.y : copysignf(scale, v.y - mean);
    v.z = (nb & 4u) ? v.z : copysignf(scale, v.z - mean);
    v.w = (nb & 8u) ? v.w : copysignf(scale, v.w - mean);
    ushort4 u;
    u.x = f2bf(v.x); u.y = f2bf(v.y); u.z = f2bf(v.z); u.w = f2bf(v.w);
    *reinterpret_cast<ushort4*>(wo + i) = u;
  }
}

// ---------------- K2: bf16 MFMA GEMM, split-K ----------------
// block = 4 waves; wave wv owns cols [tile*64 + wv*16, +16), K-chunk sk*512.
// A-frag (x): row = lane&15, k = (lane>>4)*8.. ; B-frag (w_eff): col = lane&15.
// D: col = lane&15, row(b) = (lane>>4)*4 + reg  [m89 layout].
__global__ __launch_bounds__(256) void mfma_kernel(
    const unsigned short* __restrict__ weff,
    const unsigned short* __restrict__ xbf, float* __restrict__ part) {
  const int bx = blockIdx.x;
  const int tile = bx >> 3;
  const int sk = bx & 7;
  const int t = threadIdx.x;
  const int wv = t >> 6;
  const int l = t & 63;
  const int l15 = l & 15, l4 = l >> 4;

  const int o = tile * 64 + wv * 16 + l15;
  const int k0 = sk * (IC / SKM) + l4 * 8;

  const unsigned short* bp = weff + (size_t)o * IC + k0;
  const unsigned short* ap0 = xbf + (size_t)l15 * IC + k0;
  const unsigned short* ap1 = xbf + (size_t)(16 + l15) * IC + k0;

  floatx4 acc0 = {0.f, 0.f, 0.f, 0.f};
  floatx4 acc1 = {0.f, 0.f, 0.f, 0.f};
#pragma unroll 4
  for (int kk = 0; kk < (IC / SKM) / 32; ++kk) {  // 16 iters
    const short8 bf = *reinterpret_cast<const short8*>(bp + kk * 32);
    const short8 a0 = *reinterpret_cast<const short8*>(ap0 + kk * 32);
    const short8 a1 = *reinterpret_cast<const short8*>(ap1 + kk * 32);
    acc0 = __builtin_amdgcn_mfma_f32_16x16x32_bf16(a0, bf, acc0, 0, 0, 0);
    acc1 = __builtin_amdgcn_mfma_f32_16x16x32_bf16(a1, bf, acc1, 0, 0, 0);
  }

  float* pb = part + (size_t)sk * (BATCH * OC);
#pragma unroll
  for (int r = 0; r < 4; ++r) {
    const int b0 = l4 * 4 + r;
    pb[(size_t)b0 * OC + o] = acc0[r];
    pb[(size_t)(b0 + 16) * OC + o] = acc1[r];
  }
}

__global__ __launch_bounds__(256) void reduce_kernel(
    const float* __restrict__ part, const float* __restrict__ bias,
    float* __restrict__ out, int nsk) {
  const int idx = blockIdx.x * 256 + threadIdx.x;
  if (idx < BATCH * OC) {
    const int o = idx % OC;
    float v = bias[o];
    for (int sk = 0; sk < nsk; ++sk) v += part[(size_t)sk * (BATCH * OC) + idx];
    out[idx] = v;
  }
}

// ---------------- Fallback (R3 path, f32 VALU gemv) ----------------
__global__ __launch_bounds__(256) void stats_kernel_fb(
    const int* __restrict__ mask, const float* __restrict__ w,
    float2* __restrict__ stats) {
  const int o = blockIdx.x;
  const int t = threadIdx.x;
  const float* wr = w + (size_t)o * IC;
  const int* mr = mask + (size_t)o * IC;
  float s1 = 0.f, s2 = 0.f;
#pragma unroll
  for (int q = 0; q < 4; ++q) {
    const int i = (q << 10) + (t << 2);
    const float4 wv = *reinterpret_cast<const float4*>(wr + i);
    const int4 mv = *reinterpret_cast<const int4*>(mr + i);
    const float z0 = mv.x ? 0.f : wv.x, z1 = mv.y ? 0.f : wv.y;
    const float z2 = mv.z ? 0.f : wv.z, z3 = mv.w ? 0.f : wv.w;
    s1 += z0 + z1 + z2 + z3;
    s2 += fabsf(z0) + fabsf(z1) + fabsf(z2) + fabsf(z3);
  }
#pragma unroll
  for (int off = 32; off > 0; off >>= 1) {
    s1 += __shfl_down(s1, off);
    s2 += __shfl_down(s2, off);
  }
  __shared__ float r1[4], r2[4];
  if ((t & 63) == 0) { r1[t >> 6] = s1; r2[t >> 6] = s2; }
  __syncthreads();
  if (t == 0)
    stats[o] = make_float2((r1[0] + r1[1] + r1[2] + r1[3]) * (1.0f / IC),
                           (r2[0] + r2[1] + r2[2] + r2[3]) * (1.0f / IC));
}

__global__ __launch_bounds__(256) void gemv_kernel_fb(
    const float* __restrict__ x, const float* __restrict__ w,
    const int* __restrict__ mask, const float2* __restrict__ stats,
    float* __restrict__ part) {
  const int bx = blockIdx.x;
  const int tile = bx >> 2;
  const int sk = bx & 3;
  const int t = threadIdx.x;
  const int wvid = t >> 6;
  const int lane = t & 63;
  const int il = lane & 15;
  const int bg = lane >> 4;
  const int row0 = tile * 32 + wvid * 8;
  const int i0 = sk * (IC / SKF);
  const float* wr0 = w + (size_t)row0 * IC;
  const int* mk0 = mask + (size_t)row0 * IC;
  const float* xb = x + (size_t)(bg * 8) * IC;

  float2 stv[8];
#pragma unroll
  for (int r = 0; r < 8; ++r) stv[r] = stats[row0 + r];
  float acc[8][8];
#pragma unroll
  for (int r = 0; r < 8; ++r)
#pragma unroll
    for (int j = 0; j < 8; ++j) acc[r][j] = 0.f;

  for (int s_ = 0; s_ < (IC / SKF) / 64; ++s_) {
    const int i = i0 + (s_ << 6) + (il << 2);
    float4 wf[8];
#pragma unroll
    for (int r = 0; r < 8; ++r) {
      wf[r] = *reinterpret_cast<const float4*>(wr0 + (size_t)r * IC + i);
      const int4 mv = *reinterpret_cast<const int4*>(mk0 + (size_t)r * IC + i);
      const float m = stv[r].x, sc = stv[r].y;
      wf[r].x = mv.x ? wf[r].x : copysignf(sc, wf[r].x - m);
      wf[r].y = mv.y ? wf[r].y : copysignf(sc, wf[r].y - m);
      wf[r].z = mv.z ? wf[r].z : copysignf(sc, wf[r].z - m);
      wf[r].w = mv.w ? wf[r].w : copysignf(sc, wf[r].w - m);
    }
#pragma unroll
    for (int j = 0; j < 8; ++j) {
      const float4 xv = *reinterpret_cast<const float4*>(xb + (size_t)j * IC + i);
#pragma unroll
      for (int r = 0; r < 8; ++r)
        acc[r][j] += wf[r].x * xv.x + wf[r].y * xv.y + wf[r].z * xv.z +
                     wf[r].w * xv.w;
    }
  }
#pragma unroll
  for (int off = 8; off >= 1; off >>= 1)
#pragma unroll
    for (int r = 0; r < 8; ++r)
#pragma unroll
      for (int j = 0; j < 8; ++j) acc[r][j] += __shfl_xor(acc[r][j], off);
  if (il == 0)
#pragma unroll
    for (int r = 0; r < 8; ++r)
#pragma unroll
      for (int j = 0; j < 8; ++j)
        part[(size_t)sk * (BATCH * OC) + (size_t)(bg * 8 + j) * OC +
             (row0 + r)] = acc[r][j];
}

// ---------------- launch ----------------
extern "C" void kernel_launch(void* const* d_in, const int* in_sizes, int n_in,
                              void* d_out, int out_size, void* d_ws,
                              size_t ws_size, hipStream_t stream) {
  const float* x = (const float*)d_in[0];
  const float* w = (const float*)d_in[1];
  const float* bias = (const float*)d_in[2];
  const int* mask = (const int*)d_in[3];
  float* out = (float*)d_out;

  const size_t weff_b = (size_t)OC * IC * 2;          // 90,177,536
  const size_t xbf_b = (size_t)BATCH * IC * 2;        // 262,144
  const size_t part_b = (size_t)SKM * BATCH * OC * 4; // 11,272,192

  if (ws_size >= weff_b + xbf_b + part_b) {
    unsigned short* weff = (unsigned short*)d_ws;
    unsigned short* xbf = (unsigned short*)((char*)d_ws + weff_b);
    float* part = (float*)((char*)d_ws + weff_b + xbf_b);

    fuse_kernel<<<OC + BATCH, 256, 0, stream>>>(w, mask, x, weff, xbf);
    mfma_kernel<<<(OC / 64) * SKM, 256, 0, stream>>>(weff, xbf, part);
    reduce_kernel<<<(BATCH * OC + 255) / 256, 256, 0, stream>>>(part, bias, out,
                                                                SKM);
  } else {
    float2* stats = (float2*)d_ws;
    float* part = (float*)((char*)d_ws + (size_t)OC * sizeof(float2));
    stats_kernel_fb<<<OC, 256, 0, stream>>>(mask, w, stats);
    gemv_kernel_fb<<<(OC / 32) * SKF, 256, 0, stream>>>(x, w, mask, stats, part);
    reduce_kernel<<<(BATCH * OC + 255) / 256, 256, 0, stream>>>(part, bias, out,
                                                                SKF);
  }
}